// Round 6
// baseline (127.144 us; speedup 1.0000x reference)
//
#include <hip/hip_runtime.h>

// Problem constants (from reference): B=32, T=1024, D=1024, N_ITER=256, SR=4
#define BB 32
#define TT 1024
#define DD 1024
#define NIT 256
#define SRR 4
#define CS 32            // ODE steps per staged chunk
#define K1T 128          // threads (= t values) per gw_ode block
#define KT 4             // output rows per cubic block (7-row reg window)

typedef float vf4 __attribute__((ext_vector_type(4)));   // native vec for nt-store

// ---------------------------------------------------------------------------
// Kernel 1: warp-function ODE (proven ~8 us). Block = 128 consecutive t of
// one b. Stage ds chunks into LDS (stride-33, conflict-free), register-
// double-buffered; 1-fma+clamp chain per step with 'bad'-flag exact fallback.
// ---------------------------------------------------------------------------
__global__ __launch_bounds__(K1T) void gw_ode_kernel(const float* __restrict__ ds,
                                                     float* __restrict__ f_out) {
    __shared__ float slab[(K1T + 1) * 33];     // [129][33] floats, 17 KB
    const int tid = threadIdx.x;
    const int b   = blockIdx.x >> 3;           // 8 blocks per b
    const int t0  = (blockIdx.x & 7) * K1T;
    const int t   = t0 + tid;
    const int r0  = (t < TT - 2) ? t : (TT - 2);
    const int ia  = r0 - t0;                   // slab row of d0 for this lane
    const float inv = 1.0f / (float)(NIT * SRR);
    const float lo  = -(float)r0;
    const float hi  = (float)(TT - 1 - r0);
    const bool edge = (r0 == TT - 2);

    const float4* dsv = (const float4*)ds;

    float4 buf[2][9];
#pragma unroll
    for (int it = 0; it < 8; ++it) {
        const int p = it * K1T + tid, r = p >> 3, q = p & 7;
        const int row = (t0 + r < TT - 1) ? (t0 + r) : (TT - 1);
        buf[0][it] = dsv[(size_t)(b * TT + row) * (NIT / 4) + q];
    }
    if (tid < 8) {
        const int row = (t0 + K1T < TT - 1) ? (t0 + K1T) : (TT - 1);
        buf[0][8] = dsv[(size_t)(b * TT + row) * (NIT / 4) + tid];
    }

    float g = 0.0f;
    bool bad = false;

#pragma unroll
    for (int c = 0; c < NIT / CS; ++c) {
        if (c > 0) __syncthreads();            // all lanes done with prev slab
#pragma unroll
        for (int it = 0; it < 8; ++it) {
            const int p = it * K1T + tid, r = p >> 3, q = p & 7;
            const float4 v = buf[c & 1][it];
            float* s = slab + r * 33 + q * 4;
            s[0] = v.x; s[1] = v.y; s[2] = v.z; s[3] = v.w;
        }
        if (tid < 8) {
            const float4 v = buf[c & 1][8];
            float* s = slab + K1T * 33 + tid * 4;
            s[0] = v.x; s[1] = v.y; s[2] = v.z; s[3] = v.w;
        }
        __syncthreads();
        if (c < NIT / CS - 1) {                // prefetch next chunk
#pragma unroll
            for (int it = 0; it < 8; ++it) {
                const int p = it * K1T + tid, r = p >> 3, q = p & 7;
                const int row = (t0 + r < TT - 1) ? (t0 + r) : (TT - 1);
                buf[(c + 1) & 1][it] =
                    dsv[(size_t)(b * TT + row) * (NIT / 4) + (c + 1) * (CS / 4) + q];
            }
            if (tid < 8) {
                const int row = (t0 + K1T < TT - 1) ? (t0 + K1T) : (TT - 1);
                buf[(c + 1) & 1][8] =
                    dsv[(size_t)(b * TT + row) * (NIT / 4) + (c + 1) * (CS / 4) + tid];
            }
        }
        int jstart = 0;
        if (c == 0) {
            float f0 = (float)t + slab[tid * 33] * inv;      // ds[b,t,0]
            f0 = fminf(fmaxf(f0, 0.0f), (float)(TT - 1));
            g = f0 - (float)r0;
            jstart = 1;
        }
#pragma unroll 8
        for (int j = jstart; j < CS; ++j) {
            const float d0 = slab[ia * 33 + j] * inv;
            const float d1 = slab[(ia + 1) * 33 + j] * inv;
            g = fmaf(g, 1.0f + (d1 - d0), d0);               // 1-fma chain
            g = fminf(fmaxf(g, lo), hi);                     // ref's clip
            bad |= (g < 0.0f) | ((g >= 1.0f) & !(edge & (g == hi)));
        }
    }

    float fres = (float)r0 + g;
    if (bad) {   // exact general path (exec-masked off for bench data)
        float f = (float)t + ds[(size_t)(b * TT + t) * NIT] * inv;
        f = fminf(fmaxf(f, 0.0f), (float)(TT - 1));
        for (int i = 1; i < NIT; ++i) {
            int i0 = (int)floorf(f);
            i0 = min(max(i0, 0), TT - 2);
            const float d0 = ds[(size_t)(b * TT + i0) * NIT + i] * inv;
            const float d1 = ds[(size_t)(b * TT + i0 + 1) * NIT + i] * inv;
            const float tf = f - (float)i0;
            f = fminf(fmaxf(f + d0 + tf * (d1 - d0), 0.0f), (float)(TT - 1));
        }
        fres = f;
    }
    f_out[b * TT + t] = fres;
}

// ---------------------------------------------------------------------------
// Kernel 2: Catmull-Rom resampling, KT=4 rows per block via a 7-row float4
// register window (28 VGPR — no spill, unlike the KT=16 attempt). Cuts the
// cache-path read volume 4x (1.75 rows read per row written vs 4). XCD
// chunked swizzle + nontemporal output stores kept from round 4.
// ---------------------------------------------------------------------------
__global__ __launch_bounds__(256) void cubic_kernel(const float* __restrict__ xs,
                                                    const float* __restrict__ f_in,
                                                    float* __restrict__ out) {
    // bijective chunked XCD swizzle: nwg = 8192 (divisible by 8)
    const int nwg = BB * (TT / KT);
    const int blk = (blockIdx.x & 7) * (nwg >> 3) + (blockIdx.x >> 3);
    const int b   = blk >> 8;                 // 256 blocks per batch
    const int t0  = (blk & 255) * KT;
    const int tid = threadIdx.x;              // 256 threads * float4 = D

    const float4* X = (const float4*)xs + (size_t)b * TT * (DD / 4);
    vf4* O = (vf4*)out + (size_t)b * TT * (DD / 4);

    // 7-row window t0-1 .. t0+5 (clamped), all loads issued up-front
    float4 w[KT + 3];
#pragma unroll
    for (int r = 0; r < KT + 3; ++r) {
        const int row = min(max(t0 - 1 + r, 0), TT - 1);
        w[r] = X[((size_t)row << 8) + tid];
    }
    // 4 f values (block-uniform), one aligned float4 load
    const float4 fv4 = *(const float4*)(f_in + (size_t)b * TT + t0);
    const float fvals[KT] = {fv4.x, fv4.y, fv4.z, fv4.w};

#pragma unroll
    for (int k = 0; k < KT; ++k) {
        const int t = t0 + k;
        const float f = fvals[k];
        int i1 = (int)floorf(f);
        i1 = min(max(i1, 0), TT - 1);
        const float tf = f - (float)i1;
        const float t2 = tf * tf, t3 = t2 * tf;
        const float w0 = -0.5f * t3 + t2 - 0.5f * tf;
        const float w1 = 1.5f * t3 - 2.5f * t2 + 1.0f;
        const float w2 = -1.5f * t3 + 2.0f * t2 + 0.5f * tf;
        const float w3 = 0.5f * t3 - 0.5f * t2;

        float4 q0, q1, q2, q3;
        if (i1 == t) {            // block-uniform fast path (always, bench data)
            q0 = w[k]; q1 = w[k + 1]; q2 = w[k + 2]; q3 = w[k + 3];
        } else {                  // general gather fallback (scalar-skipped)
            const int j0 = max(i1 - 1, 0);
            const int j2 = min(i1 + 1, TT - 1);
            const int j3 = min(i1 + 2, TT - 1);
            q0 = X[((size_t)j0 << 8) + tid];
            q1 = X[((size_t)i1 << 8) + tid];
            q2 = X[((size_t)j2 << 8) + tid];
            q3 = X[((size_t)j3 << 8) + tid];
        }
        vf4 v;
        v.x = w0 * q0.x + w1 * q1.x + w2 * q2.x + w3 * q3.x;
        v.y = w0 * q0.y + w1 * q1.y + w2 * q2.y + w3 * q3.y;
        v.z = w0 * q0.z + w1 * q1.z + w2 * q2.z + w3 * q3.z;
        v.w = w0 * q0.w + w1 * q1.w + w2 * q2.w + w3 * q3.w;
        __builtin_nontemporal_store(v, O + ((size_t)t << 8) + tid);
    }
}

extern "C" void kernel_launch(void* const* d_in, const int* in_sizes, int n_in,
                              void* d_out, int out_size, void* d_ws, size_t ws_size,
                              hipStream_t stream) {
    const float* xs = (const float*)d_in[0];   // (B, T, D) f32
    const float* ds = (const float*)d_in[1];   // (B, T, N_ITER) f32

    float* out_ys = (float*)d_out;                     // (B, T, D)
    float* out_f  = out_ys + (size_t)BB * TT * DD;     // (B, T)

    gw_ode_kernel<<<dim3((BB * TT) / K1T), K1T, 0, stream>>>(ds, out_f);
    cubic_kernel<<<dim3(BB * (TT / KT)), 256, 0, stream>>>(xs, out_f, out_ys);
}

// Round 7
// 49.649 us; speedup vs baseline: 2.5609x; 2.5609x over previous
//
#include <hip/hip_runtime.h>

// Problem constants (from reference): B=32, T=1024, D=1024, N_ITER=256, SR=4
#define BB 32
#define TT 1024
#define DD 1024
#define NIT 256
#define SRR 4
#define KT 8             // output rows (ODE chains) per block

typedef float vf4 __attribute__((ext_vector_type(4)));   // native vec for nt-store

// ---------------------------------------------------------------------------
// Fused kernel, take 2. Block = 8 consecutive t of one b (4096 blocks, 256 th).
//
// Phase 1 — scan-parallel ODE. The fast-path recurrence (i0 == r0, clamps
//   non-binding) is linear: g' = g*(1+(d1-d0)/1024) + d0/1024. Chain k is
//   handled by 32 lanes; lane j composes steps 8j..8j+7 into (A,B), a
//   width-32 Hillis-Steele compose-scan gives each lane its entry state,
//   then each lane REPLAYS its 8 steps with the exact sequential fma+clamp,
//   tracking the 'bad' validity flag (g must stay in [0,1), edge row may sit
//   at g==hi). Any bad lane -> chain falls back to the exact general gather
//   integration (never taken for bench data). No LDS, no long serial chain.
// Phase 2 — Catmull-Rom rows (round-4/5 structure: computed row indices,
//   4x float4 gathers, nontemporal stores). XCD chunked swizzle for L2.
// ---------------------------------------------------------------------------
__global__ __launch_bounds__(256, 4) void fused2_kernel(const float* __restrict__ xs,
                                                        const float* __restrict__ ds,
                                                        float* __restrict__ out_ys,
                                                        float* __restrict__ f_out) {
    __shared__ float fbuf[KT];

    // bijective chunked XCD swizzle over 4096 blocks (4096 % 8 == 0)
    const int nwg = BB * (TT / KT);
    const int blk = (blockIdx.x & 7) * (nwg >> 3) + (blockIdx.x >> 3);
    const int b   = blk >> 7;                 // 128 blocks per batch
    const int t0  = (blk & 127) * KT;
    const int tid = threadIdx.x;
    const float inv = 1.0f / (float)(NIT * SRR);   // 1/1024, exact

    // ---------------- Phase 1: scan-parallel ODE ----------------
    {
        const int k = tid >> 5;               // chain 0..7
        const int j = tid & 31;               // segment within chain
        const int t = t0 + k;
        const int r0 = (t < TT - 2) ? t : (TT - 2);

        // lane j loads steps 8j..8j+7 of rows r0 and r0+1 (2 float4 each)
        const float4* row0 = (const float4*)ds + (size_t)(b * TT + r0) * (NIT / 4) + j * 2;
        const float4* row1 = row0 + (NIT / 4);
        float d0v[8], d1v[8];
#pragma unroll
        for (int m = 0; m < 2; ++m) {
            const float4 u = row0[m];
            d0v[4*m+0] = u.x; d0v[4*m+1] = u.y; d0v[4*m+2] = u.z; d0v[4*m+3] = u.w;
            const float4 v = row1[m];
            d1v[4*m+0] = v.x; d1v[4*m+1] = v.y; d1v[4*m+2] = v.z; d1v[4*m+3] = v.w;
        }

        // chain init g0 (global step 0), computed on j==0, broadcast
        float g0 = 0.0f;
        if (j == 0) {
            const float dinit = (t == r0) ? d0v[0] : d1v[0];   // ds[b,t,0]
            float f0 = (float)t + dinit * inv;
            f0 = fminf(fmaxf(f0, 0.0f), (float)(TT - 1));
            g0 = f0 - (float)r0;
        }
        g0 = __shfl(g0, 0, 32);

        // local segment composition: (A,B) maps g -> A*g + B over steps 8j..8j+7
        // (global step 0 is excluded: identity on lane 0, m==0)
        float A = 1.0f, Bc = 0.0f;
#pragma unroll
        for (int m = 0; m < 8; ++m) {
            float a  = fmaf(d1v[m] - d0v[m], inv, 1.0f);
            float bb = d0v[m] * inv;
            if (m == 0) { if (j == 0) { a = 1.0f; bb = 0.0f; } }
            Bc = fmaf(Bc, a, bb);
            A  = A * a;
        }

        // width-32 Hillis-Steele inclusive compose-scan (prefix applied first)
#pragma unroll
        for (int d = 1; d < 32; d <<= 1) {
            const float Ap = __shfl_up(A, d, 32);
            const float Bp = __shfl_up(Bc, d, 32);
            if (j >= d) {
                Bc = fmaf(Bp, A, Bc);        // B = B_prev*A_cur + B_cur
                A  = A * Ap;
            }
        }

        // entry state = S_{j-1}(g0); replay own 8 steps exactly (fma + clamp)
        const float Ae = __shfl_up(A, 1, 32);
        const float Be = __shfl_up(Bc, 1, 32);
        float g = (j == 0) ? g0 : fmaf(g0, Ae, Be);

        const float lo = -(float)r0;
        const float hi = (float)(TT - 1 - r0);
        const bool edge = (r0 == TT - 2);
        bool bad = false;
#pragma unroll
        for (int m = 0; m < 8; ++m) {
            float a  = fmaf(d1v[m] - d0v[m], inv, 1.0f);
            float bb = d0v[m] * inv;
            if (m == 0) { if (j == 0) { a = 1.0f; bb = 0.0f; } }
            g = fmaf(g, a, bb);
            g = fminf(fmaxf(g, lo), hi);
            bad |= (g < 0.0f) | ((g >= 1.0f) & !(edge & (g == hi)));
        }

        const unsigned long long bm = __ballot(bad);
        const int lane = tid & 63;
        const bool chainbad = ((bm >> (lane & ~31)) & 0xFFFFFFFFull) != 0;

        if (j == 31) {
            float fres = (float)r0 + g;
            if (chainbad) {   // exact general path (exec-masked off for bench data)
                float f = (float)t + ds[(size_t)(b * TT + t) * NIT] * inv;
                f = fminf(fmaxf(f, 0.0f), (float)(TT - 1));
                for (int i = 1; i < NIT; ++i) {
                    int i0 = (int)floorf(f);
                    i0 = min(max(i0, 0), TT - 2);
                    const float dd0 = ds[(size_t)(b * TT + i0) * NIT + i] * inv;
                    const float dd1 = ds[(size_t)(b * TT + i0 + 1) * NIT + i] * inv;
                    const float tf = f - (float)i0;
                    f = fminf(fmaxf(f + dd0 + tf * (dd1 - dd0), 0.0f), (float)(TT - 1));
                }
                fres = f;
            }
            fbuf[k] = fres;
            f_out[b * TT + t] = fres;
        }
    }
    __syncthreads();

    // ---------------- Phase 2: Catmull-Rom rows ----------------
    const float4* X = (const float4*)xs + (size_t)b * TT * (DD / 4);
    vf4* O = (vf4*)out_ys;

    for (int k = 0; k < KT; ++k) {
        const float fv = fbuf[k];
        int i1 = (int)floorf(fv);
        i1 = min(max(i1, 0), TT - 1);
        const float tf = fv - (float)i1;
        const float t2 = tf * tf, t3 = t2 * tf;
        const float w0 = -0.5f * t3 + t2 - 0.5f * tf;
        const float w1 = 1.5f * t3 - 2.5f * t2 + 1.0f;
        const float w2 = -1.5f * t3 + 2.0f * t2 + 0.5f * tf;
        const float w3 = 0.5f * t3 - 0.5f * t2;

        const int j0 = max(i1 - 1, 0);
        const int j2 = min(i1 + 1, TT - 1);
        const int j3 = min(i1 + 2, TT - 1);

        const float4 p0 = X[((size_t)j0 << 8) + tid];
        const float4 p1 = X[((size_t)i1 << 8) + tid];
        const float4 p2 = X[((size_t)j2 << 8) + tid];
        const float4 p3 = X[((size_t)j3 << 8) + tid];
        vf4 v;
        v.x = w0 * p0.x + w1 * p1.x + w2 * p2.x + w3 * p3.x;
        v.y = w0 * p0.y + w1 * p1.y + w2 * p2.y + w3 * p3.y;
        v.z = w0 * p0.z + w1 * p1.z + w2 * p2.z + w3 * p3.z;
        v.w = w0 * p0.w + w1 * p1.w + w2 * p2.w + w3 * p3.w;
        __builtin_nontemporal_store(v, O + (((size_t)(b * TT + t0 + k)) << 8) + tid);
    }
}

extern "C" void kernel_launch(void* const* d_in, const int* in_sizes, int n_in,
                              void* d_out, int out_size, void* d_ws, size_t ws_size,
                              hipStream_t stream) {
    const float* xs = (const float*)d_in[0];   // (B, T, D) f32
    const float* ds = (const float*)d_in[1];   // (B, T, N_ITER) f32

    float* out_ys = (float*)d_out;                     // (B, T, D)
    float* out_f  = out_ys + (size_t)BB * TT * DD;     // (B, T)

    fused2_kernel<<<dim3(BB * (TT / KT)), 256, 0, stream>>>(xs, ds, out_ys, out_f);
}

// Round 8
// 49.021 us; speedup vs baseline: 2.5937x; 1.0128x over previous
//
#include <hip/hip_runtime.h>

// Problem constants (from reference): B=32, T=1024, D=1024, N_ITER=256, SR=4
#define BB 32
#define TT 1024
#define DD 1024
#define NIT 256
#define SRR 4
#define KT 8             // output rows (ODE chains) per block

typedef float vf4 __attribute__((ext_vector_type(4)));   // native vec for nt-store

// ---------------------------------------------------------------------------
// Fused kernel (round-7 structure + phase-2 software pipelining).
//
// Phase 1 — scan-parallel ODE (unchanged from round 7, proven):
//   linear recurrence g' = g*(1+(d1-d0)/1024) + d0/1024 composed per 8-step
//   segment, width-32 Hillis-Steele compose-scan, exact fma+clamp replay with
//   'bad'-flag fallback to the general gather integration (never taken for
//   bench data).
// Phase 2 — Catmull-Rom rows, depth-1 software pipeline: issue iteration
//   k+1's 4 row loads (addresses depend only on fbuf) before computing
//   iteration k, halving exposed L2/L3 latency. Named registers only, fully
//   unrolled — no dynamically-indexed arrays (scratch-spill trap from r2/r6).
// ---------------------------------------------------------------------------
__global__ __launch_bounds__(256, 4) void fused2_kernel(const float* __restrict__ xs,
                                                        const float* __restrict__ ds,
                                                        float* __restrict__ out_ys,
                                                        float* __restrict__ f_out) {
    __shared__ float fbuf[KT];

    // bijective chunked XCD swizzle over 4096 blocks (4096 % 8 == 0)
    const int nwg = BB * (TT / KT);
    const int blk = (blockIdx.x & 7) * (nwg >> 3) + (blockIdx.x >> 3);
    const int b   = blk >> 7;                 // 128 blocks per batch
    const int t0  = (blk & 127) * KT;
    const int tid = threadIdx.x;
    const float inv = 1.0f / (float)(NIT * SRR);   // 1/1024, exact

    // ---------------- Phase 1: scan-parallel ODE ----------------
    {
        const int k = tid >> 5;               // chain 0..7
        const int j = tid & 31;               // segment within chain
        const int t = t0 + k;
        const int r0 = (t < TT - 2) ? t : (TT - 2);

        // lane j loads steps 8j..8j+7 of rows r0 and r0+1 (2 float4 each)
        const float4* row0 = (const float4*)ds + (size_t)(b * TT + r0) * (NIT / 4) + j * 2;
        const float4* row1 = row0 + (NIT / 4);
        float d0v[8], d1v[8];
#pragma unroll
        for (int m = 0; m < 2; ++m) {
            const float4 u = row0[m];
            d0v[4*m+0] = u.x; d0v[4*m+1] = u.y; d0v[4*m+2] = u.z; d0v[4*m+3] = u.w;
            const float4 v = row1[m];
            d1v[4*m+0] = v.x; d1v[4*m+1] = v.y; d1v[4*m+2] = v.z; d1v[4*m+3] = v.w;
        }

        // chain init g0 (global step 0), computed on j==0, broadcast
        float g0 = 0.0f;
        if (j == 0) {
            const float dinit = (t == r0) ? d0v[0] : d1v[0];   // ds[b,t,0]
            float f0 = (float)t + dinit * inv;
            f0 = fminf(fmaxf(f0, 0.0f), (float)(TT - 1));
            g0 = f0 - (float)r0;
        }
        g0 = __shfl(g0, 0, 32);

        // local segment composition: (A,B) maps g -> A*g + B over steps 8j..8j+7
        float A = 1.0f, Bc = 0.0f;
#pragma unroll
        for (int m = 0; m < 8; ++m) {
            float a  = fmaf(d1v[m] - d0v[m], inv, 1.0f);
            float bb = d0v[m] * inv;
            if (m == 0) { if (j == 0) { a = 1.0f; bb = 0.0f; } }
            Bc = fmaf(Bc, a, bb);
            A  = A * a;
        }

        // width-32 Hillis-Steele inclusive compose-scan
#pragma unroll
        for (int d = 1; d < 32; d <<= 1) {
            const float Ap = __shfl_up(A, d, 32);
            const float Bp = __shfl_up(Bc, d, 32);
            if (j >= d) {
                Bc = fmaf(Bp, A, Bc);        // B = B_prev*A_cur + B_cur
                A  = A * Ap;
            }
        }

        // entry state = S_{j-1}(g0); replay own 8 steps exactly (fma + clamp)
        const float Ae = __shfl_up(A, 1, 32);
        const float Be = __shfl_up(Bc, 1, 32);
        float g = (j == 0) ? g0 : fmaf(g0, Ae, Be);

        const float lo = -(float)r0;
        const float hi = (float)(TT - 1 - r0);
        const bool edge = (r0 == TT - 2);
        bool bad = false;
#pragma unroll
        for (int m = 0; m < 8; ++m) {
            float a  = fmaf(d1v[m] - d0v[m], inv, 1.0f);
            float bb = d0v[m] * inv;
            if (m == 0) { if (j == 0) { a = 1.0f; bb = 0.0f; } }
            g = fmaf(g, a, bb);
            g = fminf(fmaxf(g, lo), hi);
            bad |= (g < 0.0f) | ((g >= 1.0f) & !(edge & (g == hi)));
        }

        const unsigned long long bm = __ballot(bad);
        const int lane = tid & 63;
        const bool chainbad = ((bm >> (lane & ~31)) & 0xFFFFFFFFull) != 0;

        if (j == 31) {
            float fres = (float)r0 + g;
            if (chainbad) {   // exact general path (exec-masked off for bench data)
                float f = (float)t + ds[(size_t)(b * TT + t) * NIT] * inv;
                f = fminf(fmaxf(f, 0.0f), (float)(TT - 1));
                for (int i = 1; i < NIT; ++i) {
                    int i0 = (int)floorf(f);
                    i0 = min(max(i0, 0), TT - 2);
                    const float dd0 = ds[(size_t)(b * TT + i0) * NIT + i] * inv;
                    const float dd1 = ds[(size_t)(b * TT + i0 + 1) * NIT + i] * inv;
                    const float tf = f - (float)i0;
                    f = fminf(fmaxf(f + dd0 + tf * (dd1 - dd0), 0.0f), (float)(TT - 1));
                }
                fres = f;
            }
            fbuf[k] = fres;
            f_out[b * TT + t] = fres;
        }
    }
    __syncthreads();

    // ---------------- Phase 2: Catmull-Rom rows, depth-1 pipeline ----------------
    const float4* X = (const float4*)xs + (size_t)b * TT * (DD / 4);
    vf4* O = (vf4*)out_ys;

    // prologue: issue k=0 loads
    float4 a0, a1, a2, a3;
    {
        const float fv = fbuf[0];
        int i1 = (int)floorf(fv);
        i1 = min(max(i1, 0), TT - 1);
        const int j0 = max(i1 - 1, 0);
        const int j2 = min(i1 + 1, TT - 1);
        const int j3 = min(i1 + 2, TT - 1);
        a0 = X[((size_t)j0 << 8) + tid];
        a1 = X[((size_t)i1 << 8) + tid];
        a2 = X[((size_t)j2 << 8) + tid];
        a3 = X[((size_t)j3 << 8) + tid];
    }

#pragma unroll
    for (int k = 0; k < KT; ++k) {
        // issue k+1's loads before consuming k's (independent: addr from fbuf)
        float4 b0 = a0, b1 = a1, b2 = a2, b3 = a3;   // init avoids maydef warnings
        if (k + 1 < KT) {
            const float fvn = fbuf[k + 1];
            int i1n = (int)floorf(fvn);
            i1n = min(max(i1n, 0), TT - 1);
            const int j0n = max(i1n - 1, 0);
            const int j2n = min(i1n + 1, TT - 1);
            const int j3n = min(i1n + 2, TT - 1);
            b0 = X[((size_t)j0n << 8) + tid];
            b1 = X[((size_t)i1n << 8) + tid];
            b2 = X[((size_t)j2n << 8) + tid];
            b3 = X[((size_t)j3n << 8) + tid];
        }

        const float fv = fbuf[k];
        int i1 = (int)floorf(fv);
        i1 = min(max(i1, 0), TT - 1);
        const float tf = fv - (float)i1;
        const float t2 = tf * tf, t3 = t2 * tf;
        const float w0 = -0.5f * t3 + t2 - 0.5f * tf;
        const float w1 = 1.5f * t3 - 2.5f * t2 + 1.0f;
        const float w2 = -1.5f * t3 + 2.0f * t2 + 0.5f * tf;
        const float w3 = 0.5f * t3 - 0.5f * t2;

        vf4 v;
        v.x = w0 * a0.x + w1 * a1.x + w2 * a2.x + w3 * a3.x;
        v.y = w0 * a0.y + w1 * a1.y + w2 * a2.y + w3 * a3.y;
        v.z = w0 * a0.z + w1 * a1.z + w2 * a2.z + w3 * a3.z;
        v.w = w0 * a0.w + w1 * a1.w + w2 * a2.w + w3 * a3.w;
        __builtin_nontemporal_store(v, O + (((size_t)(b * TT + t0 + k)) << 8) + tid);

        a0 = b0; a1 = b1; a2 = b2; a3 = b3;
    }
}

extern "C" void kernel_launch(void* const* d_in, const int* in_sizes, int n_in,
                              void* d_out, int out_size, void* d_ws, size_t ws_size,
                              hipStream_t stream) {
    const float* xs = (const float*)d_in[0];   // (B, T, D) f32
    const float* ds = (const float*)d_in[1];   // (B, T, N_ITER) f32

    float* out_ys = (float*)d_out;                     // (B, T, D)
    float* out_f  = out_ys + (size_t)BB * TT * DD;     // (B, T)

    fused2_kernel<<<dim3(BB * (TT / KT)), 256, 0, stream>>>(xs, ds, out_ys, out_f);
}

// Round 9
// 48.823 us; speedup vs baseline: 2.6042x; 1.0041x over previous
//
#include <hip/hip_runtime.h>

// Problem constants (from reference): B=32, T=1024, D=1024, N_ITER=256, SR=4
#define BB 32
#define TT 1024
#define DD 1024
#define NIT 256
#define SRR 4
#define KT 8             // output rows (ODE chains) per block

typedef float vf4 __attribute__((ext_vector_type(4)));   // native vec for nt-store

// ---------------------------------------------------------------------------
// Fused kernel, take 3.
//
// Entry — issue the 11 fixed window-row loads (rows t0-1..t0+9, independent
//   of f!) into NAMED float4 registers; they stream in underneath phase 1.
//   (Named scalars, never arrays: r2/r6 showed float4 arrays fail SROA and
//   spill to scratch; named float4 a0..a3 in r7/r8 never spilled.)
// Phase 1 — scan-parallel ODE (unchanged, proven): linear recurrence
//   composed per 8-step segment, width-32 Hillis-Steele compose-scan, exact
//   fma+clamp replay with 'bad'-flag fallback to the general integration.
// Phase 2 — Catmull-Rom rows from the register window: pure FMA + nt-store.
//   Fast path requires i1 == t (block-uniform; true for all bench rows except
//   t==1023); fallback does the 4 gather loads (uniform branch, rare).
// ---------------------------------------------------------------------------
__global__ __launch_bounds__(256, 4) void fused3_kernel(const float* __restrict__ xs,
                                                        const float* __restrict__ ds,
                                                        float* __restrict__ out_ys,
                                                        float* __restrict__ f_out) {
    __shared__ float fbuf[KT];

    // bijective chunked XCD swizzle over 4096 blocks (4096 % 8 == 0)
    const int nwg = BB * (TT / KT);
    const int blk = (blockIdx.x & 7) * (nwg >> 3) + (blockIdx.x >> 3);
    const int b   = blk >> 7;                 // 128 blocks per batch
    const int t0  = (blk & 127) * KT;
    const int tid = threadIdx.x;
    const float inv = 1.0f / (float)(NIT * SRR);   // 1/1024, exact

    // ---- Entry: 11 window-row loads (addresses independent of phase 1) ----
    const float4* X = (const float4*)xs + (size_t)b * TT * (DD / 4);
#define WROW(r) X[((size_t)min(max(t0 - 1 + (r), 0), TT - 1) << 8) + tid]
    const float4 wA = WROW(0), wB = WROW(1), wC = WROW(2), wD = WROW(3);
    const float4 wE = WROW(4), wF = WROW(5), wG = WROW(6), wH = WROW(7);
    const float4 wI = WROW(8), wJ = WROW(9), wK = WROW(10);
#undef WROW

    // ---------------- Phase 1: scan-parallel ODE ----------------
    {
        const int k = tid >> 5;               // chain 0..7
        const int j = tid & 31;               // segment within chain
        const int t = t0 + k;
        const int r0 = (t < TT - 2) ? t : (TT - 2);

        // lane j loads steps 8j..8j+7 of rows r0 and r0+1 (2 float4 each)
        const float4* row0 = (const float4*)ds + (size_t)(b * TT + r0) * (NIT / 4) + j * 2;
        const float4* row1 = row0 + (NIT / 4);
        float d0v[8], d1v[8];
#pragma unroll
        for (int m = 0; m < 2; ++m) {
            const float4 u = row0[m];
            d0v[4*m+0] = u.x; d0v[4*m+1] = u.y; d0v[4*m+2] = u.z; d0v[4*m+3] = u.w;
            const float4 v = row1[m];
            d1v[4*m+0] = v.x; d1v[4*m+1] = v.y; d1v[4*m+2] = v.z; d1v[4*m+3] = v.w;
        }

        // chain init g0 (global step 0), computed on j==0, broadcast
        float g0 = 0.0f;
        if (j == 0) {
            const float dinit = (t == r0) ? d0v[0] : d1v[0];   // ds[b,t,0]
            float f0 = (float)t + dinit * inv;
            f0 = fminf(fmaxf(f0, 0.0f), (float)(TT - 1));
            g0 = f0 - (float)r0;
        }
        g0 = __shfl(g0, 0, 32);

        // local segment composition: (A,B) maps g -> A*g + B over steps 8j..8j+7
        float A = 1.0f, Bc = 0.0f;
#pragma unroll
        for (int m = 0; m < 8; ++m) {
            float a  = fmaf(d1v[m] - d0v[m], inv, 1.0f);
            float bb = d0v[m] * inv;
            if (m == 0) { if (j == 0) { a = 1.0f; bb = 0.0f; } }
            Bc = fmaf(Bc, a, bb);
            A  = A * a;
        }

        // width-32 Hillis-Steele inclusive compose-scan
#pragma unroll
        for (int d = 1; d < 32; d <<= 1) {
            const float Ap = __shfl_up(A, d, 32);
            const float Bp = __shfl_up(Bc, d, 32);
            if (j >= d) {
                Bc = fmaf(Bp, A, Bc);        // B = B_prev*A_cur + B_cur
                A  = A * Ap;
            }
        }

        // entry state = S_{j-1}(g0); replay own 8 steps exactly (fma + clamp)
        const float Ae = __shfl_up(A, 1, 32);
        const float Be = __shfl_up(Bc, 1, 32);
        float g = (j == 0) ? g0 : fmaf(g0, Ae, Be);

        const float lo = -(float)r0;
        const float hi = (float)(TT - 1 - r0);
        const bool edge = (r0 == TT - 2);
        bool bad = false;
#pragma unroll
        for (int m = 0; m < 8; ++m) {
            float a  = fmaf(d1v[m] - d0v[m], inv, 1.0f);
            float bb = d0v[m] * inv;
            if (m == 0) { if (j == 0) { a = 1.0f; bb = 0.0f; } }
            g = fmaf(g, a, bb);
            g = fminf(fmaxf(g, lo), hi);
            bad |= (g < 0.0f) | ((g >= 1.0f) & !(edge & (g == hi)));
        }

        const unsigned long long bm = __ballot(bad);
        const int lane = tid & 63;
        const bool chainbad = ((bm >> (lane & ~31)) & 0xFFFFFFFFull) != 0;

        if (j == 31) {
            float fres = (float)r0 + g;
            if (chainbad) {   // exact general path (exec-masked off for bench data)
                float f = (float)t + ds[(size_t)(b * TT + t) * NIT] * inv;
                f = fminf(fmaxf(f, 0.0f), (float)(TT - 1));
                for (int i = 1; i < NIT; ++i) {
                    int i0 = (int)floorf(f);
                    i0 = min(max(i0, 0), TT - 2);
                    const float dd0 = ds[(size_t)(b * TT + i0) * NIT + i] * inv;
                    const float dd1 = ds[(size_t)(b * TT + i0 + 1) * NIT + i] * inv;
                    const float tf = f - (float)i0;
                    f = fminf(fmaxf(f + dd0 + tf * (dd1 - dd0), 0.0f), (float)(TT - 1));
                }
                fres = f;
            }
            fbuf[k] = fres;
            f_out[b * TT + t] = fres;
        }
    }
    __syncthreads();

    // ---------------- Phase 2: Catmull-Rom rows from register window ----------------
    vf4* O = (vf4*)out_ys;

#define CUBIC_K(k, q0, q1, q2, q3)                                                   \
    {                                                                                \
        const int t = t0 + (k);                                                      \
        const float fv = fbuf[(k)];                                                  \
        int i1 = (int)floorf(fv);                                                    \
        i1 = min(max(i1, 0), TT - 1);                                                \
        const float tf = fv - (float)i1;                                             \
        const float t2 = tf * tf, t3 = t2 * tf;                                      \
        const float c0 = -0.5f * t3 + t2 - 0.5f * tf;                                \
        const float c1 = 1.5f * t3 - 2.5f * t2 + 1.0f;                               \
        const float c2 = -1.5f * t3 + 2.0f * t2 + 0.5f * tf;                         \
        const float c3 = 0.5f * t3 - 0.5f * t2;                                      \
        float4 p0, p1, p2, p3;                                                       \
        if (i1 == t) {              /* block-uniform fast path */                    \
            p0 = (q0); p1 = (q1); p2 = (q2); p3 = (q3);                              \
        } else {                    /* general gather fallback (rare) */             \
            const int j0 = max(i1 - 1, 0);                                           \
            const int j2 = min(i1 + 1, TT - 1);                                      \
            const int j3 = min(i1 + 2, TT - 1);                                      \
            p0 = X[((size_t)j0 << 8) + tid];                                         \
            p1 = X[((size_t)i1 << 8) + tid];                                         \
            p2 = X[((size_t)j2 << 8) + tid];                                         \
            p3 = X[((size_t)j3 << 8) + tid];                                         \
        }                                                                            \
        vf4 v;                                                                       \
        v.x = c0 * p0.x + c1 * p1.x + c2 * p2.x + c3 * p3.x;                         \
        v.y = c0 * p0.y + c1 * p1.y + c2 * p2.y + c3 * p3.y;                         \
        v.z = c0 * p0.z + c1 * p1.z + c2 * p2.z + c3 * p3.z;                         \
        v.w = c0 * p0.w + c1 * p1.w + c2 * p2.w + c3 * p3.w;                         \
        __builtin_nontemporal_store(v, O + (((size_t)(b * TT + t)) << 8) + tid);     \
    }

    CUBIC_K(0, wA, wB, wC, wD)
    CUBIC_K(1, wB, wC, wD, wE)
    CUBIC_K(2, wC, wD, wE, wF)
    CUBIC_K(3, wD, wE, wF, wG)
    CUBIC_K(4, wE, wF, wG, wH)
    CUBIC_K(5, wF, wG, wH, wI)
    CUBIC_K(6, wG, wH, wI, wJ)
    CUBIC_K(7, wH, wI, wJ, wK)
#undef CUBIC_K
}

extern "C" void kernel_launch(void* const* d_in, const int* in_sizes, int n_in,
                              void* d_out, int out_size, void* d_ws, size_t ws_size,
                              hipStream_t stream) {
    const float* xs = (const float*)d_in[0];   // (B, T, D) f32
    const float* ds = (const float*)d_in[1];   // (B, T, N_ITER) f32

    float* out_ys = (float*)d_out;                     // (B, T, D)
    float* out_f  = out_ys + (size_t)BB * TT * DD;     // (B, T)

    fused3_kernel<<<dim3(BB * (TT / KT)), 256, 0, stream>>>(xs, ds, out_ys, out_f);
}

// Round 10
// 48.263 us; speedup vs baseline: 2.6344x; 1.0116x over previous
//
#include <hip/hip_runtime.h>

// Problem constants (from reference): B=32, T=1024, D=1024, N_ITER=256, SR=4
#define BB 32
#define TT 1024
#define DD 1024
#define NIT 256
#define SRR 4
#define KT 8             // output rows (ODE chains) per block

typedef float vf4 __attribute__((ext_vector_type(4)));   // native vec for nt-store

// ---------------------------------------------------------------------------
// Fused kernel, take 4 (= take 3 with the load-ordering bug fixed).
//
// Entry — issue the 4 ds loads FIRST, then the 11 fixed xs window-row loads
//   (rows t0-1..t0+9, independent of f). vmcnt completion is in-order: phase
//   1's wait on ds now drains only the ds loads, and the 44 KB xs stream
//   stays in flight underneath the scan + ballot + barrier. (In round 9 the
//   xs loads were issued first, so phase 1 implicitly waited for ALL of them
//   — the overlap never happened.)
// Phase 1 — scan-parallel ODE (proven): linear recurrence composed per
//   8-step segment, width-32 Hillis-Steele compose-scan, exact fma+clamp
//   replay with 'bad'-flag fallback to the general gather integration.
// Phase 2 — Catmull-Rom rows from the named register window: FMA + nt-store.
//   Fast path i1 == t (block-uniform); gather fallback for the edge row /
//   hypothetical bad data.
// ---------------------------------------------------------------------------
__global__ __launch_bounds__(256, 4) void fused4_kernel(const float* __restrict__ xs,
                                                        const float* __restrict__ ds,
                                                        float* __restrict__ out_ys,
                                                        float* __restrict__ f_out) {
    __shared__ float fbuf[KT];

    // bijective chunked XCD swizzle over 4096 blocks (4096 % 8 == 0)
    const int nwg = BB * (TT / KT);
    const int blk = (blockIdx.x & 7) * (nwg >> 3) + (blockIdx.x >> 3);
    const int b   = blk >> 7;                 // 128 blocks per batch
    const int t0  = (blk & 127) * KT;
    const int tid = threadIdx.x;
    const float inv = 1.0f / (float)(NIT * SRR);   // 1/1024, exact

    // ---- ds loads FIRST (phase 1 consumes these; oldest in vmcnt queue) ----
    const int k = tid >> 5;                   // chain 0..7
    const int j = tid & 31;                   // segment within chain
    const int t = t0 + k;
    const int r0 = (t < TT - 2) ? t : (TT - 2);

    const float4* row0 = (const float4*)ds + (size_t)(b * TT + r0) * (NIT / 4) + j * 2;
    const float4* row1 = row0 + (NIT / 4);
    const float4 u0 = row0[0], u1 = row0[1];  // steps 8j..8j+7 of row r0
    const float4 v0 = row1[0], v1 = row1[1];  // steps 8j..8j+7 of row r0+1

    // ---- then the 11 xs window-row loads (consumed after the barrier) ----
    const float4* X = (const float4*)xs + (size_t)b * TT * (DD / 4);
#define WROW(r) X[((size_t)min(max(t0 - 1 + (r), 0), TT - 1) << 8) + tid]
    const float4 wA = WROW(0), wB = WROW(1), wC = WROW(2), wD = WROW(3);
    const float4 wE = WROW(4), wF = WROW(5), wG = WROW(6), wH = WROW(7);
    const float4 wI = WROW(8), wJ = WROW(9), wK = WROW(10);
#undef WROW

    // ---------------- Phase 1: scan-parallel ODE ----------------
    {
        float d0v[8], d1v[8];
        d0v[0] = u0.x; d0v[1] = u0.y; d0v[2] = u0.z; d0v[3] = u0.w;
        d0v[4] = u1.x; d0v[5] = u1.y; d0v[6] = u1.z; d0v[7] = u1.w;
        d1v[0] = v0.x; d1v[1] = v0.y; d1v[2] = v0.z; d1v[3] = v0.w;
        d1v[4] = v1.x; d1v[5] = v1.y; d1v[6] = v1.z; d1v[7] = v1.w;

        // chain init g0 (global step 0), computed on j==0, broadcast
        float g0 = 0.0f;
        if (j == 0) {
            const float dinit = (t == r0) ? d0v[0] : d1v[0];   // ds[b,t,0]
            float f0 = (float)t + dinit * inv;
            f0 = fminf(fmaxf(f0, 0.0f), (float)(TT - 1));
            g0 = f0 - (float)r0;
        }
        g0 = __shfl(g0, 0, 32);

        // local segment composition: (A,B) maps g -> A*g + B over steps 8j..8j+7
        float A = 1.0f, Bc = 0.0f;
#pragma unroll
        for (int m = 0; m < 8; ++m) {
            float a  = fmaf(d1v[m] - d0v[m], inv, 1.0f);
            float bb = d0v[m] * inv;
            if (m == 0) { if (j == 0) { a = 1.0f; bb = 0.0f; } }
            Bc = fmaf(Bc, a, bb);
            A  = A * a;
        }

        // width-32 Hillis-Steele inclusive compose-scan
#pragma unroll
        for (int d = 1; d < 32; d <<= 1) {
            const float Ap = __shfl_up(A, d, 32);
            const float Bp = __shfl_up(Bc, d, 32);
            if (j >= d) {
                Bc = fmaf(Bp, A, Bc);        // B = B_prev*A_cur + B_cur
                A  = A * Ap;
            }
        }

        // entry state = S_{j-1}(g0); replay own 8 steps exactly (fma + clamp)
        const float Ae = __shfl_up(A, 1, 32);
        const float Be = __shfl_up(Bc, 1, 32);
        float g = (j == 0) ? g0 : fmaf(g0, Ae, Be);

        const float lo = -(float)r0;
        const float hi = (float)(TT - 1 - r0);
        const bool edge = (r0 == TT - 2);
        bool bad = false;
#pragma unroll
        for (int m = 0; m < 8; ++m) {
            float a  = fmaf(d1v[m] - d0v[m], inv, 1.0f);
            float bb = d0v[m] * inv;
            if (m == 0) { if (j == 0) { a = 1.0f; bb = 0.0f; } }
            g = fmaf(g, a, bb);
            g = fminf(fmaxf(g, lo), hi);
            bad |= (g < 0.0f) | ((g >= 1.0f) & !(edge & (g == hi)));
        }

        const unsigned long long bm = __ballot(bad);
        const int lane = tid & 63;
        const bool chainbad = ((bm >> (lane & ~31)) & 0xFFFFFFFFull) != 0;

        if (j == 31) {
            float fres = (float)r0 + g;
            if (chainbad) {   // exact general path (exec-masked off for bench data)
                float f = (float)t + ds[(size_t)(b * TT + t) * NIT] * inv;
                f = fminf(fmaxf(f, 0.0f), (float)(TT - 1));
                for (int i = 1; i < NIT; ++i) {
                    int i0 = (int)floorf(f);
                    i0 = min(max(i0, 0), TT - 2);
                    const float dd0 = ds[(size_t)(b * TT + i0) * NIT + i] * inv;
                    const float dd1 = ds[(size_t)(b * TT + i0 + 1) * NIT + i] * inv;
                    const float tf = f - (float)i0;
                    f = fminf(fmaxf(f + dd0 + tf * (dd1 - dd0), 0.0f), (float)(TT - 1));
                }
                fres = f;
            }
            fbuf[k] = fres;
            f_out[b * TT + t] = fres;
        }
    }
    __syncthreads();

    // ---------------- Phase 2: Catmull-Rom rows from register window ----------------
    vf4* O = (vf4*)out_ys;

#define CUBIC_K(kk, q0, q1, q2, q3)                                                  \
    {                                                                                \
        const int tt = t0 + (kk);                                                    \
        const float fv = fbuf[(kk)];                                                 \
        int i1 = (int)floorf(fv);                                                    \
        i1 = min(max(i1, 0), TT - 1);                                                \
        const float tf = fv - (float)i1;                                             \
        const float t2 = tf * tf, t3 = t2 * tf;                                      \
        const float c0 = -0.5f * t3 + t2 - 0.5f * tf;                                \
        const float c1 = 1.5f * t3 - 2.5f * t2 + 1.0f;                               \
        const float c2 = -1.5f * t3 + 2.0f * t2 + 0.5f * tf;                         \
        const float c3 = 0.5f * t3 - 0.5f * t2;                                      \
        float4 p0, p1, p2, p3;                                                       \
        if (i1 == tt) {             /* block-uniform fast path */                    \
            p0 = (q0); p1 = (q1); p2 = (q2); p3 = (q3);                              \
        } else {                    /* general gather fallback (rare) */             \
            const int j0 = max(i1 - 1, 0);                                           \
            const int j2 = min(i1 + 1, TT - 1);                                      \
            const int j3 = min(i1 + 2, TT - 1);                                      \
            p0 = X[((size_t)j0 << 8) + tid];                                         \
            p1 = X[((size_t)i1 << 8) + tid];                                         \
            p2 = X[((size_t)j2 << 8) + tid];                                         \
            p3 = X[((size_t)j3 << 8) + tid];                                         \
        }                                                                            \
        vf4 v;                                                                       \
        v.x = c0 * p0.x + c1 * p1.x + c2 * p2.x + c3 * p3.x;                         \
        v.y = c0 * p0.y + c1 * p1.y + c2 * p2.y + c3 * p3.y;                         \
        v.z = c0 * p0.z + c1 * p1.z + c2 * p2.z + c3 * p3.z;                         \
        v.w = c0 * p0.w + c1 * p1.w + c2 * p2.w + c3 * p3.w;                         \
        __builtin_nontemporal_store(v, O + (((size_t)(b * TT + tt)) << 8) + tid);    \
    }

    CUBIC_K(0, wA, wB, wC, wD)
    CUBIC_K(1, wB, wC, wD, wE)
    CUBIC_K(2, wC, wD, wE, wF)
    CUBIC_K(3, wD, wE, wF, wG)
    CUBIC_K(4, wE, wF, wG, wH)
    CUBIC_K(5, wF, wG, wH, wI)
    CUBIC_K(6, wG, wH, wI, wJ)
    CUBIC_K(7, wH, wI, wJ, wK)
#undef CUBIC_K
}

extern "C" void kernel_launch(void* const* d_in, const int* in_sizes, int n_in,
                              void* d_out, int out_size, void* d_ws, size_t ws_size,
                              hipStream_t stream) {
    const float* xs = (const float*)d_in[0];   // (B, T, D) f32
    const float* ds = (const float*)d_in[1];   // (B, T, N_ITER) f32

    float* out_ys = (float*)d_out;                     // (B, T, D)
    float* out_f  = out_ys + (size_t)BB * TT * DD;     // (B, T)

    fused4_kernel<<<dim3(BB * (TT / KT)), 256, 0, stream>>>(xs, ds, out_ys, out_f);
}